// Round 1
// baseline (287.133 us; speedup 1.0000x reference)
//
#include <hip/hip_runtime.h>
#include <stdint.h>

#define MDIM 8192
#define NDIM 1536
#define KDIM 3072

#define BM 128
#define BN 128
#define BK 32

typedef unsigned short u16;
typedef float  f32x4  __attribute__((ext_vector_type(4)));
typedef __bf16 bf16x8 __attribute__((ext_vector_type(8)));

__device__ __forceinline__ u16 f2bf(float f) {
    union { float f; unsigned int u; } v; v.f = f;
    unsigned int u = v.u;
    return (u16)((u + 0x7fffu + ((u >> 16) & 1u)) >> 16);  // RNE
}

// ---------------- prep 1: x fp32 -> bf16 ----------------
__global__ void cvt_x_kernel(const float4* __restrict__ x, ushort4* __restrict__ xb) {
    int i = blockIdx.x * 256 + threadIdx.x;   // grid sized exactly: no bounds check
    float4 v = x[i];
    ushort4 o;
    o.x = f2bf(v.x); o.y = f2bf(v.y); o.z = f2bf(v.z); o.w = f2bf(v.w);
    xb[i] = o;
}

// ------- prep 2: Bt[n][k] = bf16(mask[n][k] * w[k][n]) -------
// 64x64 tiles; w tile transposed through LDS so both global reads and the
// write are coalesced.
__global__ void make_b_kernel(const float* __restrict__ w, const float* __restrict__ mask,
                              u16* __restrict__ Bt) {
    __shared__ float sw[64][65];   // +1 pad: phase-2 reads land 2-way (free)
    const int t  = threadIdx.x;
    const int kb = blockIdx.x % (KDIM / 64);
    const int nb = blockIdx.x / (KDIM / 64);
    const int k0 = kb * 64, n0 = nb * 64;

    // phase 1: stage w[k0..k0+63][n0..n0+63], coalesced float4 reads
    {
        const int c4 = t & 15;   // float4 column within tile
        const int r  = t >> 4;   // 0..15
#pragma unroll
        for (int rr = 0; rr < 4; ++rr) {
            int row = rr * 16 + r;
            float4 v = *(const float4*)&w[(size_t)(k0 + row) * NDIM + n0 + c4 * 4];
            sw[row][c4 * 4 + 0] = v.x;
            sw[row][c4 * 4 + 1] = v.y;
            sw[row][c4 * 4 + 2] = v.z;
            sw[row][c4 * 4 + 3] = v.w;
        }
    }
    __syncthreads();
    // phase 2: mask read + Bt write coalesced along k; w comes transposed from LDS
    {
        const int n  = t >> 2;          // 0..63
        const int ks = (t & 3) * 16;    // 0,16,32,48
#pragma unroll
        for (int j = 0; j < 4; ++j) {
            int k = ks + j * 4;
            float4 mv = *(const float4*)&mask[(size_t)(n0 + n) * KDIM + k0 + k];
            ushort4 o;
            o.x = f2bf(mv.x * sw[k + 0][n]);
            o.y = f2bf(mv.y * sw[k + 1][n]);
            o.z = f2bf(mv.z * sw[k + 2][n]);
            o.w = f2bf(mv.w * sw[k + 3][n]);
            *(ushort4*)&Bt[(size_t)(n0 + n) * KDIM + k0 + k] = o;
        }
    }
}

// ---------------- GEMM: C[m][n] = sum_k A[m][k]*Bt[n][k] + bias[n] ----------------
// m97-style: 128x128 tile, BK=32, 4 waves, each wave 64x64 = 4x4 MFMA 16x16x32 bf16,
// global_load_lds width=16 staging (LDS dest = wave-uniform base + lane*16, so the
// LDS layout is exactly lane-ordered: row = lane>>2, colchunk = lane&3).
__device__ __forceinline__ void gload_lds16(const u16* g, u16* l) {
    __builtin_amdgcn_global_load_lds(
        (const __attribute__((address_space(1))) unsigned int*)g,
        (__attribute__((address_space(3))) unsigned int*)l, 16, 0, 0);
}

__global__ void gemm_kernel(const u16* __restrict__ A,   // [M][K] bf16
                            const u16* __restrict__ B,   // [N][K] bf16 (= mask.T*w, transposed)
                            const float* __restrict__ bias,
                            float* __restrict__ C) {     // [M][N] fp32
    __shared__ u16 sA[BM * BK];   // 8 KiB
    __shared__ u16 sB[BN * BK];   // 8 KiB

    const int tid  = threadIdx.x;
    const int wave = tid >> 6;
    const int lane = tid & 63;

    const int bx = blockIdx.x % (NDIM / BN);   // 12 n-blocks
    const int by = blockIdx.x / (NDIM / BN);   // 64 m-blocks
    const int m0 = by * BM, n0 = bx * BN;

    // staging: each wave instr covers 16 rows x 32 bf16 (64 lanes * 16B)
    const int srow = lane >> 2;         // 0..15
    const int scol = (lane & 3) * 8;    // element offset within row

    // compute: wave -> 64x64 quadrant
    const int wm = (wave >> 1) * 64;
    const int wn = (wave & 1) * 64;
    const int fr = lane & 15;   // fragment row (m for A, n for B, col for C/D)
    const int fq = lane >> 4;   // quad: k-chunk for A/B, row-group for C/D

    f32x4 acc[4][4] = {};

    const u16* gA0 = A + (size_t)(m0 + wave * 16 + srow) * KDIM + scol;
    const u16* gB0 = B + (size_t)(n0 + wave * 16 + srow) * KDIM + scol;
    u16* lA0 = &sA[(wave * 16) * BK];
    u16* lA1 = &sA[(wave * 16 + 64) * BK];
    u16* lB0 = &sB[(wave * 16) * BK];
    u16* lB1 = &sB[(wave * 16 + 64) * BK];

    for (int k0 = 0; k0 < KDIM; k0 += BK) {
        __syncthreads();   // previous iteration's ds_reads complete
        gload_lds16(gA0 + k0,                      lA0);
        gload_lds16(gA0 + k0 + (size_t)64 * KDIM,  lA1);
        gload_lds16(gB0 + k0,                      lB0);
        gload_lds16(gB0 + k0 + (size_t)64 * KDIM,  lB1);
        __syncthreads();   // staging drained (compiler emits vmcnt(0) before barrier)

        bf16x8 af[4], bfv[4];
#pragma unroll
        for (int mt = 0; mt < 4; ++mt)
            af[mt] = *(const bf16x8*)&sA[(wm + mt * 16 + fr) * BK + fq * 8];
#pragma unroll
        for (int nt = 0; nt < 4; ++nt)
            bfv[nt] = *(const bf16x8*)&sB[(wn + nt * 16 + fr) * BK + fq * 8];
#pragma unroll
        for (int mt = 0; mt < 4; ++mt)
#pragma unroll
            for (int nt = 0; nt < 4; ++nt)
                acc[mt][nt] = __builtin_amdgcn_mfma_f32_16x16x32_bf16(
                    af[mt], bfv[nt], acc[mt][nt], 0, 0, 0);
    }

    // epilogue: C/D layout col = lane&15, row = (lane>>4)*4 + reg  [m89-verified]
#pragma unroll
    for (int nt = 0; nt < 4; ++nt) {
        int n = n0 + wn + nt * 16 + fr;
        float bv = bias[n];
#pragma unroll
        for (int mt = 0; mt < 4; ++mt) {
            int m = m0 + wm + mt * 16 + fq * 4;
#pragma unroll
            for (int r = 0; r < 4; ++r)
                C[(size_t)(m + r) * NDIM + n] = acc[mt][nt][r] + bv;
        }
    }
}

extern "C" void kernel_launch(void* const* d_in, const int* in_sizes, int n_in,
                              void* d_out, int out_size, void* d_ws, size_t ws_size,
                              hipStream_t stream) {
    const float* x    = (const float*)d_in[0];   // [8192][3072]
    const float* w    = (const float*)d_in[1];   // [3072][1536]
    const float* bias = (const float*)d_in[2];   // [1536]
    const float* mask = (const float*)d_in[3];   // [1536][3072]
    float* out = (float*)d_out;                  // [8192][1536]

    u16* xb = (u16*)d_ws;                                   // 8192*3072*2  = 50331648 B
    u16* Bt = (u16*)((char*)d_ws + (size_t)50331648);       // 1536*3072*2  =  9437184 B

    cvt_x_kernel<<<(MDIM * KDIM / 4) / 256, 256, 0, stream>>>(
        (const float4*)x, (ushort4*)xb);
    make_b_kernel<<<(KDIM / 64) * (NDIM / 64), 256, 0, stream>>>(w, mask, Bt);
    gemm_kernel<<<(MDIM / BM) * (NDIM / BN), 256, 0, stream>>>(xb, Bt, bias, out);
}

// Round 2
// 286.752 us; speedup vs baseline: 1.0013x; 1.0013x over previous
//
#include <hip/hip_runtime.h>
#include <stdint.h>

#define MDIM 8192
#define NDIM 1536
#define KDIM 3072

#define BM 128
#define BN 128
#define BK 32

#define NMB ((KDIM / 64) * (NDIM / 64))          // 1152 make_b blocks
#define NCVT ((MDIM * KDIM / 4) / 256)           // 24576 cvt blocks

typedef unsigned short u16;
typedef float  f32x4  __attribute__((ext_vector_type(4)));
typedef __bf16 bf16x8 __attribute__((ext_vector_type(8)));

__device__ __forceinline__ u16 f2bf(float f) {
    union { float f; unsigned int u; } v; v.f = f;
    unsigned int u = v.u;
    return (u16)((u + 0x7fffu + ((u >> 16) & 1u)) >> 16);  // RNE
}

// ---------------- fused prep: make_b blocks first, then cvt_x blocks ----------------
// make_b: Bt[n][k] = bf16(mask[n][k] * w[k][n])  (w transposed through LDS)
// cvt:    xb = bf16(x)
__global__ void prep_kernel(const float* __restrict__ w, const float* __restrict__ mask,
                            u16* __restrict__ Bt,
                            const float4* __restrict__ x, ushort4* __restrict__ xb) {
    const int t = threadIdx.x;
    if (blockIdx.x < NMB) {
        __shared__ float sw[64][65];
        const int kb = blockIdx.x % (KDIM / 64);
        const int nb = blockIdx.x / (KDIM / 64);
        const int k0 = kb * 64, n0 = nb * 64;
        {
            const int c4 = t & 15;
            const int r  = t >> 4;
#pragma unroll
            for (int rr = 0; rr < 4; ++rr) {
                int row = rr * 16 + r;
                float4 v = *(const float4*)&w[(size_t)(k0 + row) * NDIM + n0 + c4 * 4];
                sw[row][c4 * 4 + 0] = v.x;
                sw[row][c4 * 4 + 1] = v.y;
                sw[row][c4 * 4 + 2] = v.z;
                sw[row][c4 * 4 + 3] = v.w;
            }
        }
        __syncthreads();
        {
            const int n  = t >> 2;
            const int ks = (t & 3) * 16;
#pragma unroll
            for (int j = 0; j < 4; ++j) {
                int k = ks + j * 4;
                float4 mv = *(const float4*)&mask[(size_t)(n0 + n) * KDIM + k0 + k];
                ushort4 o;
                o.x = f2bf(mv.x * sw[k + 0][n]);
                o.y = f2bf(mv.y * sw[k + 1][n]);
                o.z = f2bf(mv.z * sw[k + 2][n]);
                o.w = f2bf(mv.w * sw[k + 3][n]);
                *(ushort4*)&Bt[(size_t)(n0 + n) * KDIM + k0 + k] = o;
            }
        }
    } else {
        int i = (blockIdx.x - NMB) * 256 + t;
        float4 v = x[i];
        ushort4 o;
        o.x = f2bf(v.x); o.y = f2bf(v.y); o.z = f2bf(v.z); o.w = f2bf(v.w);
        xb[i] = o;
    }
}

// ---------------- GEMM: C[m][n] = sum_k A[m][k]*Bt[n][k] + bias[n] ----------------
// 128x128 tile, BK=32, 4 waves x (4x4) mfma 16x16x32 bf16, global_load_lds w=16.
// LDS layout XOR-swizzled: 16B chunk (row r, kchunk c) lives at slot 4r + (c ^ ((r>>1)&3)).
// global_load_lds dest is lane-ordered (slot = lane), so the swizzle is applied to the
// GLOBAL source address per lane; fragment ds_reads then spread over all 8 chunk
// positions (2 lanes each = free 2-way) instead of 2 positions (8-way conflict).
__device__ __forceinline__ void gload_lds16(const u16* g, u16* l) {
    __builtin_amdgcn_global_load_lds(
        (const __attribute__((address_space(1))) unsigned int*)g,
        (__attribute__((address_space(3))) unsigned int*)l, 16, 0, 0);
}

__global__ void gemm_kernel(const u16* __restrict__ A,   // [M][K] bf16
                            const u16* __restrict__ B,   // [N][K] bf16
                            const float* __restrict__ bias,
                            float* __restrict__ C) {     // [M][N] fp32
    __shared__ u16 sA[BM * BK];   // 8 KiB
    __shared__ u16 sB[BN * BK];   // 8 KiB

    const int tid  = threadIdx.x;
    const int wave = tid >> 6;
    const int lane = tid & 63;

    const int bx = blockIdx.x % (NDIM / BN);
    const int by = blockIdx.x / (NDIM / BN);
    const int m0 = by * BM, n0 = bx * BN;

    // staging: lane l stages global chunk (row = l>>2, c = (l&3) ^ ((l>>3)&3))
    // into LDS slot l  ->  slot = 4r + (c ^ ((r>>1)&3))   [(l>>3)&3 == ((l>>2)>>1)&3]
    const int srow = lane >> 2;
    const int scol = ((lane & 3) ^ ((lane >> 3) & 3)) * 8;

    const int wm = (wave >> 1) * 64;
    const int wn = (wave & 1) * 64;
    const int fr = lane & 15;
    const int fq = lane >> 4;
    const int fsw = (fq ^ ((fr >> 1) & 3)) * 8;   // swizzled chunk offset within a row

    f32x4 acc[4][4] = {};

    const u16* gA0 = A + (size_t)(m0 + wave * 16 + srow) * KDIM + scol;
    const u16* gB0 = B + (size_t)(n0 + wave * 16 + srow) * KDIM + scol;
    u16* lA0 = &sA[(wave * 16) * BK];
    u16* lA1 = &sA[(wave * 16 + 64) * BK];
    u16* lB0 = &sB[(wave * 16) * BK];
    u16* lB1 = &sB[(wave * 16 + 64) * BK];

    for (int k0 = 0; k0 < KDIM; k0 += BK) {
        __syncthreads();
        gload_lds16(gA0 + k0,                      lA0);
        gload_lds16(gA0 + k0 + (size_t)64 * KDIM,  lA1);
        gload_lds16(gB0 + k0,                      lB0);
        gload_lds16(gB0 + k0 + (size_t)64 * KDIM,  lB1);
        __syncthreads();

        bf16x8 af[4], bfv[4];
#pragma unroll
        for (int mt = 0; mt < 4; ++mt)
            af[mt] = *(const bf16x8*)&sA[(wm + mt * 16 + fr) * BK + fsw];
#pragma unroll
        for (int nt = 0; nt < 4; ++nt)
            bfv[nt] = *(const bf16x8*)&sB[(wn + nt * 16 + fr) * BK + fsw];
#pragma unroll
        for (int mt = 0; mt < 4; ++mt)
#pragma unroll
            for (int nt = 0; nt < 4; ++nt)
                acc[mt][nt] = __builtin_amdgcn_mfma_f32_16x16x32_bf16(
                    af[mt], bfv[nt], acc[mt][nt], 0, 0, 0);
    }

    // epilogue: C/D layout col = lane&15, row = (lane>>4)*4 + reg  [m89-verified]
#pragma unroll
    for (int nt = 0; nt < 4; ++nt) {
        int n = n0 + wn + nt * 16 + fr;
        float bv = bias[n];
#pragma unroll
        for (int mt = 0; mt < 4; ++mt) {
            int m = m0 + wm + mt * 16 + fq * 4;
#pragma unroll
            for (int r = 0; r < 4; ++r)
                C[(size_t)(m + r) * NDIM + n] = acc[mt][nt][r] + bv;
        }
    }
}

extern "C" void kernel_launch(void* const* d_in, const int* in_sizes, int n_in,
                              void* d_out, int out_size, void* d_ws, size_t ws_size,
                              hipStream_t stream) {
    const float* x    = (const float*)d_in[0];   // [8192][3072]
    const float* w    = (const float*)d_in[1];   // [3072][1536]
    const float* bias = (const float*)d_in[2];   // [1536]
    const float* mask = (const float*)d_in[3];   // [1536][3072]
    float* out = (float*)d_out;                  // [8192][1536]

    u16* xb = (u16*)d_ws;                                   // 50331648 B
    u16* Bt = (u16*)((char*)d_ws + (size_t)50331648);       //  9437184 B

    prep_kernel<<<NMB + NCVT, 256, 0, stream>>>(w, mask, Bt, (const float4*)x, (ushort4*)xb);
    gemm_kernel<<<(MDIM / BM) * (NDIM / BN), 256, 0, stream>>>(xb, Bt, bias, out);
}